// Round 7
// baseline (11165.304 us; speedup 1.0000x reference)
//
#include <hip/hip_runtime.h>
#include <math.h>

#define TT 19
#define TPREV 10

typedef __attribute__((ext_vector_type(8))) short bf8v;
typedef __attribute__((ext_vector_type(4))) float f4v;
typedef __attribute__((ext_vector_type(16))) float f16v;

__device__ __forceinline__ float sigmoidf_(float x){ return 1.f/(1.f+expf(-x)); }
__device__ __forceinline__ unsigned short f2bf(float x){
    unsigned int u = __float_as_uint(x);
    u += 0x7FFFu + ((u>>16)&1u);
    return (unsigned short)(u>>16);
}
__device__ __forceinline__ float bf2f(unsigned short b){ return __uint_as_float(((unsigned int)b)<<16); }

// RULE (R4, keep forever): NEVER use the offset-immediate arg of
// global_load_lds — it corrupts the LDS destination address. offset=0 +
// explicit pointer arithmetic only.
#define GLDS(g, l) __builtin_amdgcn_global_load_lds( \
    (const __attribute__((address_space(1))) void*)(g),   \
    (__attribute__((address_space(3))) void*)(l), 16, 0, 0)

struct HSeg {
    const unsigned short* in;
    int cl;        // log2(Cin) of the input buffer layout (5,7,8)
    int c0;        // absolute ci base
    int nch;       // number of 32-ci chunks
    int tap0, ntaps, five;
};
struct HJob {
    const unsigned short* wt;   // tile stream
    float* out;
    int cout_stride, pad;
    HSeg s;
};
struct HJobs14 { HJob j[14]; };
struct HJobs9  { HJob j[9]; };

// sH PLANE LAYOUT (kept from R4; verified 8.7M -> 1.3M conflicts):
// 4 ci-octet planes x [cell][8 shorts]; B-read = 16B/lane stride ->
// any 8 consecutive lanes cover all 32 banks once.
__device__ __forceinline__ void stage_halo(
    unsigned short* sH, const unsigned short* inb, int cl, int c0,
    int y0, int tid)
{
#pragma unroll
    for (int k = 0; k < 8; ++k) {
        const int s = tid + k * 256;
        if (s < 1920) {
            const int r = s / 160;
            const int rem = s - r * 160;
            const int cc = rem >> 2, G = rem & 3;
            const int y = y0 + r - 2, x = cc - 4;
            const bool okv = ((unsigned)y < 32u) & ((unsigned)x < 32u);
            const int yc = okv ? y : 0, xc = okv ? x : 0;
            bf8v v = *(const bf8v*)(inb + ((((yc << 5) + xc)) << cl) + c0 + G * 8);
            if (!okv) v = (bf8v)(short)0;
            *(bf8v*)&sH[(G * 480 + r * 40 + cc) * 8] = v;
        }
    }
}

// ------------------------------------------------------------------
// hconvA (R7): T3/T4-faithful tap loop — READS BEFORE THE BARRIER.
//   R6 post-mortem: per-SIMD pipe utilizations are MFMA ~9%, LDS ~23%,
//   VALU 8% — the kernel is LATENCY-bound, not pipe-bound. R4/R5/R6
//   all placed ds_reads AFTER the barrier: every wave ate the full LDS
//   read latency between barrier release and its MFMA cluster.
//   This version (m201 template ordering):
//     issue GLDS(t+2) ; rdA(t)+rdB(t) [issued, NOT waited] ;
//     s_waitcnt vmcnt(2) ; s_barrier(t) ;
//     setprio(1) ; 16 MFMA (compiler emits counted lgkm) ; setprio(0)
//   Read latency drains under barrier-arrival skew; MFMA starts
//   near-operand-ready; vmcnt is counted (2), NEVER a full drain in
//   the steady loop; lgkm untouched by GLDS (vmcnt-counted op).
//   Safety ledger (4 x 8KB slots, slot = tile&3):
//   - tile t resident at rdA(t): every wave's vmcnt(2) at tap t-1
//     (outstanding {t,t+1} -> retires t) precedes barrier(t-1);
//     rdA(t) is after barrier(t-1). ✓
//   - slot (t+2)&3 overwrite at issue(t): that slot's last reads
//     (tap t-2) completed before MFMA(t-2) (compiler lgkm) -> before
//     barrier(t-1) -> before issue(t). ✓
//   - tail: t+2>=ntot -> vmcnt(0) (queue nearly empty, exact).
//   - chunk restage: __syncthreads pair (vmcnt0+lgkm0+barrier); the
//     drain self-resyncs the vmcnt ledger (traced t, t+1 cases).
//   - barrier counts block-uniform -> no deadlock.
// ------------------------------------------------------------------
template<typename JOBS>
__global__ __launch_bounds__(256, 2) void hconvA_kernel(JOBS jobs)
{
    __shared__ unsigned short sA[16384];   // 4 tile slots x 8KB
    __shared__ unsigned short sH[15360];   // 4 planes x 480 cells x 8 shorts
    const int tid = threadIdx.x;

    // XCD-clustered job mapping (requires nb%8==0, gridDim.x==32)
    const int nb   = gridDim.x * gridDim.y;
    const int per8 = nb >> 3;
    const int bidl = blockIdx.x + gridDim.x * blockIdx.y;
    const int g    = (bidl & 7) * per8 + (bidl >> 3);
    const int jy   = g >> 5;
    const int xt   = g & 31;
    const HJob jb = jobs.j[jy];

    const int ng0 = xt << 8;
    const int bb = ng0 >> 10, p0 = ng0 & 1023;
    const int y0 = p0 >> 5;          // {0,8,16,24}

    const int lane = tid & 63, wv = tid >> 6;
    const int wm = (wv & 1) << 6;    // M base 0/64
    const int wn = (wv >> 1) << 7;   // N base 0/128
    const int col = lane & 31, ll5 = lane >> 5;

    int bofs0[4];
#pragma unroll
    for (int ni = 0; ni < 4; ++ni) {
        const int ln = wn + ni * 32 + col;
        const int cell = ((ln >> 5) + 2) * 40 + (ln & 31) + 4;
        bofs0[ni] = cell * 8 + ll5 * 3840;
    }
    const int rowA0 = (wm + col) * 8;
    const int oA = ll5 * 1024;

    f16v acc[2][4];
#pragma unroll
    for (int i = 0; i < 2; ++i)
#pragma unroll
        for (int j = 0; j < 4; ++j) acc[i][j] = (f16v)0.f;

    const HSeg sg = jb.s;
    const unsigned short* inb = sg.in + ((size_t)bb << (10 + sg.cl));
    const unsigned short* wissue = jb.wt;
    const int nch = sg.nch;
    const int ntot = nch * 25;

    bf8v av[2][2], bv[2][4];

    auto issue = [&](int gt1) {
        const int sl = (gt1 & 3) * 4096;
        GLDS(wissue + tid * 8,         &sA[sl + tid * 8]);
        GLDS(wissue + (tid + 256) * 8, &sA[sl + (tid + 256) * 8]);
        wissue += 4096;
    };

    // ---- prologue ----
    stage_halo(sH, inb, sg.cl, sg.c0, y0, tid);
    issue(0);
    issue(1);
    asm volatile("s_waitcnt vmcnt(2) lgkmcnt(0)" ::: "memory");
    __builtin_amdgcn_s_barrier();

    int gt = 0;
    for (int c = 0; c < nch; ++c) {
        if (c > 0) {
            __syncthreads();    // all sH readers done; drains (ledger resyncs)
            stage_halo(sH, inb, sg.cl, sg.c0 + c * 32, y0, tid);
            __syncthreads();    // all waves' sH writes visible
        }
        for (int tc = 0; tc < 25; ++tc, ++gt) {
            // [I] next-next tile into its slot (counted, stays in flight)
            if (gt + 2 < ntot) issue(gt + 2);
            // [R] all 12 ds_reads for tap gt — issued, not waited
            {
                const unsigned short* sAb = &sA[(gt & 3) * 4096];
#pragma unroll
                for (int s = 0; s < 2; ++s)
#pragma unroll
                    for (int mi = 0; mi < 2; ++mi)
                        av[s][mi] = *(const bf8v*)&sAb[s * 2048 + oA + rowA0 + mi * 256];
                const int t5 = (tc * 52) >> 8;
                const int tO = ((t5 - 2) * 40 + (tc - t5 * 5 - 2)) * 8;
#pragma unroll
                for (int s = 0; s < 2; ++s)
#pragma unroll
                    for (int ni = 0; ni < 4; ++ni)
                        bv[s][ni] = *(const bf8v*)&sH[bofs0[ni] + tO + s * 7680];
            }
            // [W] counted: retire tile gt+1 (resident for next tap's reads)
            if (gt + 2 < ntot) asm volatile("s_waitcnt vmcnt(2)" ::: "memory");
            else               asm volatile("s_waitcnt vmcnt(0)" ::: "memory");
            __builtin_amdgcn_s_barrier();
            // [M] MFMA cluster; compiler inserts counted lgkm waits
            __builtin_amdgcn_s_setprio(1);
#pragma unroll
            for (int s = 0; s < 2; ++s)
#pragma unroll
                for (int mi = 0; mi < 2; ++mi)
#pragma unroll
                    for (int ni = 0; ni < 4; ++ni)
                        acc[mi][ni] = __builtin_amdgcn_mfma_f32_32x32x16_bf16(
                            av[s][mi], bv[s][ni], acc[mi][ni], 0, 0, 0);
            __builtin_amdgcn_s_setprio(0);
        }
    }

    // epilogue (32x32 C/D): col=lane&31, row=(reg&3)+8*(reg>>2)+4*ll5
    const int nfix = ng0 + wn + col;
#pragma unroll
    for (int ni = 0; ni < 4; ++ni) {
        const int n = nfix + ni * 32;
        float* ob = jb.out + (size_t)n * jb.cout_stride;
#pragma unroll
        for (int mi = 0; mi < 2; ++mi) {
            const int mb = wm + mi * 32 + 4 * ll5;
            const f16v a = acc[mi][ni];
#pragma unroll
            for (int qd = 0; qd < 4; ++qd) {
                f4v v;
                v[0] = a[qd * 4 + 0]; v[1] = a[qd * 4 + 1];
                v[2] = a[qd * 4 + 2]; v[3] = a[qd * 4 + 3];
                *(f4v*)(ob + mb + qd * 8) = v;
            }
        }
    }
}

// ------------------------------------------------------------------
// hconv: classic 2-phase stream conv (phase B: many short jobs, 576
// blocks). sH plane layout (4 planes x 320 cells x 8 shorts).
// ------------------------------------------------------------------
template<typename JOBS>
__global__ __launch_bounds__(256) void hconv_kernel(JOBS jobs)
{
    __shared__ unsigned short sA[8192];    // 2 x 8KB tile buffers
    __shared__ unsigned short sH[10240];   // 4 planes x 320 cells x 8 shorts
    const HJob jb = jobs.j[blockIdx.y];
    const int tid = threadIdx.x;

    const int ng0 = blockIdx.x * 128;
    const int bb = ng0 >> 10, p0 = ng0 & 1023;
    const int y0 = p0 >> 5;

    const int lane = tid & 63, wv = tid >> 6;
    const int wm = (wv & 1) << 6;
    const int wn = (wv >> 1) << 6;
    const int col = lane & 31, ll5 = lane >> 5;

    int bofs0[2];
#pragma unroll
    for (int ni = 0; ni < 2; ++ni) {
        const int ln = wn + ni * 32 + col;
        const int cell = ((ln >> 5) + 2) * 40 + (ln & 31) + 4;
        bofs0[ni] = cell * 8 + ll5 * 2560;
    }

    f16v acc[2][2];
#pragma unroll
    for (int i = 0; i < 2; ++i)
#pragma unroll
        for (int j = 0; j < 2; ++j) acc[i][j] = (f16v)0.f;

    const HSeg sg = jb.s;
    const unsigned short* inb = sg.in + ((size_t)bb << (10 + sg.cl));
    const unsigned short* wptr = jb.wt;
    int buf = 0;
    bool first = true;
    for (int ch = 0; ch < sg.nch; ++ch) {
        const int c0 = sg.c0 + ch * 32;
#pragma unroll
        for (int k = 0; k < 5; ++k) {
            const int s = tid + k * 256;
            const int r = s / 160;
            const int rem = s - r * 160;
            const int cc = rem >> 2, G = rem & 3;
            const int y = y0 + r - 2, x = cc - 4;
            const bool okv = ((unsigned)y < 32u) & ((unsigned)x < 32u);
            const int yc = okv ? y : 0, xc = okv ? x : 0;
            bf8v v = *(const bf8v*)(inb + ((((yc << 5) + xc)) << sg.cl) + c0 + G * 8);
            if (!okv) v = (bf8v)(short)0;
            *(bf8v*)&sH[(G * 320 + r * 40 + cc) * 8] = v;
        }
        if (first) {
            GLDS(wptr + tid * 8,         &sA[tid * 8]);
            GLDS(wptr + (tid + 256) * 8, &sA[(tid + 256) * 8]);
            wptr += 4096;
            first = false;
        }
        __syncthreads();
        for (int t = 0; t < sg.ntaps; ++t) {
            GLDS(wptr + tid * 8,         &sA[(buf ^ 1) * 4096 + tid * 8]);
            GLDS(wptr + (tid + 256) * 8, &sA[(buf ^ 1) * 4096 + (tid + 256) * 8]);
            wptr += 4096;
            int tO = 0;
            if (sg.five) {
                const int tap = sg.tap0 + t;
                const int t5 = (tap * 52) >> 8;
                tO = ((t5 - 2) * 40 + (tap - t5 * 5 - 2)) * 8;
            }
            const unsigned short* sAb = &sA[buf * 4096];
#pragma unroll
            for (int s = 0; s < 2; ++s) {
                const int o = s * 2 + ll5;
                bf8v av[2], bv[2];
#pragma unroll
                for (int mi = 0; mi < 2; ++mi)
                    av[mi] = *(const bf8v*)&sAb[(o * 128 + wm + mi * 32 + col) * 8];
#pragma unroll
                for (int ni = 0; ni < 2; ++ni)
                    bv[ni] = *(const bf8v*)&sH[bofs0[ni] + tO + s * 5120];
#pragma unroll
                for (int mi = 0; mi < 2; ++mi)
#pragma unroll
                    for (int ni = 0; ni < 2; ++ni)
                        acc[mi][ni] = __builtin_amdgcn_mfma_f32_32x32x16_bf16(
                            av[mi], bv[ni], acc[mi][ni], 0, 0, 0);
            }
            __syncthreads();
            buf ^= 1;
        }
    }

    const int nfix = ng0 + wn + col;
#pragma unroll
    for (int ni = 0; ni < 2; ++ni) {
        const int n = nfix + ni * 32;
        float* ob = jb.out + (size_t)n * jb.cout_stride;
#pragma unroll
        for (int mi = 0; mi < 2; ++mi) {
            const int mb = wm + mi * 32 + 4 * ll5;
            const f16v a = acc[mi][ni];
#pragma unroll
            for (int qd = 0; qd < 4; ++qd) {
                f4v v;
                v[0] = a[qd * 4 + 0]; v[1] = a[qd * 4 + 1];
                v[2] = a[qd * 4 + 2]; v[3] = a[qd * 4 + 3];
                *(f4v*)(ob + mb + qd * 8) = v;
            }
        }
    }
}

// ------------------------------------------------------------------
// packT: OIHW f32 -> linear tile stream [at][oct][row][8] bf16.
// ------------------------------------------------------------------
__global__ __launch_bounds__(256) void packT_kernel(
    const float* __restrict__ src, unsigned short* __restrict__ dst,
    int Cin, int srcTaps, int rowOff, int ci0, int ntaps, int tap0,
    int ciMax, int total)
{
    const int idx = blockIdx.x * 256 + threadIdx.x;
    if (idx >= total) return;
    const int j = idx & 7;
    const int row = (idx >> 3) & 127;
    const int q = (idx >> 10) & 3;
    const int at = idx >> 12;
    const int ch = at / ntaps;
    const int tap = tap0 + (at - ch * ntaps);
    const int ci = ci0 + ch * 32 + q * 8 + j;
    float v = 0.f;
    if (ci < ciMax)
        v = src[((size_t)(rowOff + row) * Cin + ci) * srcTaps + tap];
    dst[idx] = f2bf(v);
}

__global__ __launch_bounds__(256) void net_kernel(
    const float* __restrict__ frames, const float* __restrict__ mask,
    const float* __restrict__ xgen, unsigned short* __restrict__ net, int t)
{
    const int idx = blockIdx.x * 256 + threadIdx.x;  // 8192*32
    const int n = idx >> 5, ch = idx & 31;
    float v = 0.f;
    if (ch < 16) {
        const int b = n >> 10, p = n & 1023;
        const float fr = frames[((((size_t)b * 20 + t) << 10) + p) * 16 + ch];
        if (t < TPREV) v = fr;
        else {
            const float mk = mask[((((size_t)b * 9 + (t - TPREV)) << 10) + p) * 16 + ch];
            v = mk * fr + (1.f - mk) * xgen[(size_t)n * 16 + ch];
        }
    }
    net[idx] = f2bf(v);
}

__global__ __launch_bounds__(256) void gates_kernel(
    const float* __restrict__ preA, const float* __restrict__ preB,
    float* __restrict__ c, float* __restrict__ m,
    unsigned short* __restrict__ m_bf, unsigned short* __restrict__ mem)
{
    const int idx = blockIdx.x * 256 + threadIdx.x;  // 8192*128
    const int n = idx >> 7, ch = idx & 127;
    const float* pa = preA + (size_t)n * 896 + ch;
    const float* pb = preB + (size_t)n * 896 + ch;
    const float i_ = pa[0]   + pb[0];
    const float f_ = pa[128] + pb[128];
    const float g_ = pa[256] + pb[256];
    const float ip = pa[384] + pb[384];
    const float fp = pa[512] + pb[512];
    const float gp = pa[640] + pb[640];
    const float cn = sigmoidf_(f_ + 1.f) * c[idx] + sigmoidf_(i_) * tanhf(g_);
    const float mn = sigmoidf_(fp + 1.f) * m[idx] + sigmoidf_(ip) * tanhf(gp);
    c[idx] = cn;
    m[idx] = mn;
    m_bf[idx] = f2bf(mn);
    mem[(size_t)n * 256 + ch] = f2bf(cn);
    mem[(size_t)n * 256 + 128 + ch] = f2bf(mn);
}

__global__ __launch_bounds__(256) void hout_kernel(
    const float* __restrict__ preA, const float* __restrict__ preB,
    const float* __restrict__ opart, const float* __restrict__ lconv,
    unsigned short* __restrict__ h)
{
    const int idx = blockIdx.x * 256 + threadIdx.x;  // 8192*128
    const int n = idx >> 7, ch = idx & 127;
    float oc = preA[(size_t)n * 896 + 768 + ch] + preB[(size_t)n * 896 + 768 + ch];
#pragma unroll
    for (int j = 0; j < 8; ++j) oc += opart[idx + (size_t)j * 1048576];
    h[idx] = f2bf(sigmoidf_(oc) * tanhf(lconv[idx]));
}

__global__ __launch_bounds__(256) void wout_kernel(
    const unsigned short* __restrict__ h3, const float* __restrict__ wo,
    float* __restrict__ xgen, float* __restrict__ out, int t)
{
    const int idx = blockIdx.x * 256 + threadIdx.x;  // 8192*16
    const int n = idx >> 4, ch = idx & 15;
    const int b = n >> 10, p = n & 1023;
    const unsigned short* hr = h3 + (size_t)n * 128;
    const float* wr = wo + ch * 128;
    float acc = 0.f;
#pragma unroll 8
    for (int ci = 0; ci < 128; ++ci)
        acc = fmaf(bf2f(hr[ci]), wr[ci], acc);
    xgen[idx] = acc;
    out[((((size_t)b * TT + t) << 10) + p) * 16 + ch] = acc;
}

extern "C" void kernel_launch(void* const* d_in, const int* in_sizes, int n_in,
                              void* d_out, int out_size, void* d_ws, size_t ws_size,
                              hipStream_t stream)
{
    const float* frames = (const float*)d_in[0];
    const float* mask   = (const float*)d_in[1];
    const float* Wx0    = (const float*)d_in[2];
    const float* Wx     = (const float*)d_in[3];
    const float* Wh     = (const float*)d_in[4];
    const float* Wm     = (const float*)d_in[5];
    const float* Wo     = (const float*)d_in[6];
    const float* Wl     = (const float*)d_in[7];
    const float* Wout   = (const float*)d_in[8];
    float* out = (float*)d_out;

    char* base = (char*)d_ws;
    size_t off = 0;
    auto take = [&](size_t bytes) -> char* {
        char* p = base + off;
        off = (off + bytes + 255) & ~(size_t)255;
        return p;
    };
    // ---- zero-init region ----
    float* c0            = (float*)take(4ull * 1048576 * 4);
    float* m32           = (float*)take((size_t)1048576 * 4);
    unsigned short* hbf  = (unsigned short*)take(4ull * 1048576 * 2);
    unsigned short* mbf  = (unsigned short*)take((size_t)1048576 * 2);
    const size_t zbytes = off;
    // ---- working buffers ----
    float* xgen          = (float*)take((size_t)131072 * 4);
    float* preA          = (float*)take((size_t)8192 * 896 * 4);
    float* preB          = (float*)take((size_t)8192 * 896 * 4);
    float* lconv         = (float*)take((size_t)1048576 * 4);
    float* opart         = (float*)take(8ull * 1048576 * 4);
    unsigned short* net  = (unsigned short*)take((size_t)262144 * 2);   // [8192][32]
    unsigned short* mem  = (unsigned short*)take((size_t)2097152 * 2);
    // ---- packed weights (tile streams; +4096 el pad) ----
    unsigned short* pa0xT = (unsigned short*)take(((size_t)7 * 25 * 4096 + 4096) * 2);
    unsigned short* paT0 = (unsigned short*)take(((size_t)7 * 100 * 4096 + 4096) * 2);
    unsigned short* paT1 = (unsigned short*)take(((size_t)7 * 200 * 4096 + 4096) * 2);
    unsigned short* paT2 = (unsigned short*)take(((size_t)7 * 200 * 4096 + 4096) * 2);
    unsigned short* paT3 = (unsigned short*)take(((size_t)7 * 200 * 4096 + 4096) * 2);
    unsigned short* paT[4] = { paT0, paT1, paT2, paT3 };
    unsigned short* oT   = (unsigned short*)take((4ull * 200 * 4096 + 4096) * 2);
    unsigned short* lT   = (unsigned short*)take((4ull * 8 * 4096 + 4096) * 2);

    hipMemsetAsync(d_ws, 0, zbytes, stream);

    auto packT = [&](const float* s, unsigned short* d, int Cin, int srcTaps,
                     int rowOff, int ci0, int nch, int ntaps, int tap0, int ciMax) {
        const int total = nch * ntaps * 4096;
        packT_kernel<<<(total + 255) / 256, 256, 0, stream>>>(
            s, d, Cin, srcTaps, rowOff, ci0, ntaps, tap0, ciMax, total);
    };
    const int CIMAXBIG = 1 << 30;
    for (int g = 0; g < 7; ++g) {
        packT(Wx0, pa0xT + (size_t)g * 25 * 4096, 16, 25, g * 128, 0, 1, 25, 0, 16);
        const float* hm0 = (g < 3) ? (Wh + (size_t)g * 128 * 128 * 25)
                         : (g == 6) ? (Wh + (size_t)384 * 128 * 25)
                                    : (Wm + (size_t)(g - 3) * 128 * 128 * 25);
        packT(hm0, paT0 + (size_t)g * 100 * 4096, 128, 25, 0, 0, 4, 25, 0, CIMAXBIG);
        for (int l = 1; l < 4; ++l) {
            packT(Wx + (size_t)(l - 1) * 896 * 128 * 25,
                  paT[l] + (size_t)g * 200 * 4096, 128, 25, g * 128, 0, 4, 25, 0, CIMAXBIG);
            const float* hmsrc = (g < 3) ? (Wh + ((size_t)l * 512 + g * 128) * 128 * 25)
                               : (g == 6) ? (Wh + ((size_t)l * 512 + 384) * 128 * 25)
                                          : (Wm + ((size_t)l * 384 + (g - 3) * 128) * 128 * 25);
            packT(hmsrc, paT[l] + ((size_t)g * 200 + 100) * 4096, 128, 25, 0, 0, 4, 25, 0, CIMAXBIG);
        }
    }
    for (int l = 0; l < 4; ++l) {
        packT(Wo + (size_t)l * 128 * 256 * 25, oT + (size_t)l * 200 * 4096,
              256, 25, 0, 0, 8, 25, 0, CIMAXBIG);
        packT(Wl + (size_t)l * 128 * 256, lT + (size_t)l * 8 * 4096,
              256, 1, 0, 0, 8, 1, 0, CIMAXBIG);
    }

    for (int t = 0; t < TT; ++t) {
        net_kernel<<<1024, 256, 0, stream>>>(frames, mask, xgen, net, t);
        for (int l = 0; l < 4; ++l) {
            unsigned short* hl = hbf + (size_t)l * 1048576;
            // ---- phase A: one hconvA dispatch of 14 jobs ----
            HJobs14 JA{};
            if (l == 0) {
                for (int g = 0; g < 7; ++g) {
                    const unsigned short* hmsrc = (g < 3 || g == 6) ? hl : mbf;
                    JA.j[2 * g] = HJob{ pa0xT + (size_t)g * 25 * 4096, preA + g * 128,
                                        896, 0, HSeg{ net, 5, 0, 1, 0, 25, 1 } };
                    JA.j[2 * g + 1] = HJob{ paT0 + (size_t)g * 100 * 4096, preB + g * 128,
                                            896, 0, HSeg{ hmsrc, 7, 0, 4, 0, 25, 1 } };
                }
            } else {
                for (int g = 0; g < 7; ++g) {
                    const unsigned short* hmsrc = (g < 3 || g == 6) ? hl : mbf;
                    JA.j[g] = HJob{ paT[l] + (size_t)g * 200 * 4096, preA + g * 128,
                                    896, 0, HSeg{ hbf + (size_t)(l - 1) * 1048576, 7, 0, 4, 0, 25, 1 } };
                    JA.j[7 + g] = HJob{ paT[l] + ((size_t)g * 200 + 100) * 4096, preB + g * 128,
                                        896, 0, HSeg{ hmsrc, 7, 0, 4, 0, 25, 1 } };
                }
            }
            hconvA_kernel<HJobs14><<<dim3(32, 14), 256, 0, stream>>>(JA);

            gates_kernel<<<4096, 256, 0, stream>>>(preA, preB,
                c0 + (size_t)l * 1048576, m32, mbf, mem);

            // ---- phase B: o-conv split by ci-chunk x8 + lconv (classic kernel)
            HJobs9 JB{};
            for (int jj = 0; jj < 8; ++jj)
                JB.j[jj] = HJob{ oT + ((size_t)l * 200 + jj * 25) * 4096,
                                 opart + (size_t)jj * 1048576, 128, 0,
                                 HSeg{ mem, 8, jj * 32, 1, 0, 25, 1 } };
            JB.j[8] = HJob{ lT + (size_t)l * 8 * 4096, lconv, 128, 0,
                            HSeg{ mem, 8, 0, 8, 0, 1, 0 } };
            hconv_kernel<HJobs9><<<dim3(64, 9), 256, 0, stream>>>(JB);

            hout_kernel<<<4096, 256, 0, stream>>>(preA, preB, opart, lconv, hl);
        }
        wout_kernel<<<512, 256, 0, stream>>>(hbf + (size_t)3 * 1048576, Wout, xgen, out, t);
    }
}

// Round 8
// 10038.370 us; speedup vs baseline: 1.1123x; 1.1123x over previous
//
#include <hip/hip_runtime.h>
#include <math.h>

#define TT 19
#define TPREV 10

typedef __attribute__((ext_vector_type(8))) short bf8v;
typedef __attribute__((ext_vector_type(4))) float f4v;
typedef __attribute__((ext_vector_type(16))) float f16v;

__device__ __forceinline__ float sigmoidf_(float x){ return 1.f/(1.f+expf(-x)); }
__device__ __forceinline__ unsigned short f2bf(float x){
    unsigned int u = __float_as_uint(x);
    u += 0x7FFFu + ((u>>16)&1u);
    return (unsigned short)(u>>16);
}
__device__ __forceinline__ float bf2f(unsigned short b){ return __uint_as_float(((unsigned int)b)<<16); }

// RULE (R4, keep forever): NEVER use the offset-immediate arg of
// global_load_lds — it corrupts the LDS destination address. offset=0 +
// explicit pointer arithmetic only. (Used only in hconv_kernel now.)
#define GLDS(g, l) __builtin_amdgcn_global_load_lds( \
    (const __attribute__((address_space(1))) void*)(g),   \
    (__attribute__((address_space(3))) void*)(l), 16, 0, 0)

struct HSeg {
    const unsigned short* in;
    int cl;        // log2(Cin) of the input buffer layout (5,7,8)
    int c0;        // absolute ci base
    int nch;       // number of 32-ci chunks
    int tap0, ntaps, five;
};
struct HJob {
    const unsigned short* wt;   // tile stream
    float* out;
    int cout_stride, pad;
    HSeg s;
};
struct HJobs14 { HJob j[14]; };
struct HJobs9  { HJob j[9]; };

// sH PLANE LAYOUT (kept from R4; verified 8.7M -> 1.3M conflicts):
// 4 ci-octet planes x [cell][8 shorts]; B-read = 16B/lane stride ->
// any 8 consecutive lanes cover all 32 banks once.
__device__ __forceinline__ void stage_halo(
    unsigned short* sH, const unsigned short* inb, int cl, int c0,
    int y0, int tid)
{
#pragma unroll
    for (int k = 0; k < 8; ++k) {
        const int s = tid + k * 256;
        if (s < 1920) {
            const int r = s / 160;
            const int rem = s - r * 160;
            const int cc = rem >> 2, G = rem & 3;
            const int y = y0 + r - 2, x = cc - 4;
            const bool okv = ((unsigned)y < 32u) & ((unsigned)x < 32u);
            const int yc = okv ? y : 0, xc = okv ? x : 0;
            bf8v v = *(const bf8v*)(inb + ((((yc << 5) + xc)) << cl) + c0 + G * 8);
            if (!okv) v = (bf8v)(short)0;
            *(bf8v*)&sH[(G * 480 + r * 40 + cc) * 8] = v;
        }
    }
}

// ------------------------------------------------------------------
// hconvA (R8): A from GLOBAL to REGISTERS; no per-tap barrier.
//   R4-R7 post-mortem: four schedule variants all ~110 us because the
//   shared structure (A via LDS + per-tap barrier + vmcnt gate) was
//   the bottleneck: 12 ds_reads/wave/tap (per-CU LDS floor 42 us) and
//   a 100-barrier convoy that defeats TLP. Nothing was pipe-bound.
//   This version removes the structure:
//   - A-fragments (4 x 16B/lane, coalesced 512B runs) are loaded
//     straight from the packed weight stream into registers,
//     double-buffered (avA/avB), distance-1 prefetch. XCD-clustered
//     jobs keep each stream L2-resident (<=1.4MB vs 4MB/XCD L2),
//     so these are ~200cyc L2 hits hidden under the MFMA window.
//   - sH (B operand) is chunk-constant -> with A out of LDS there is
//     NO per-tap barrier. Only the restage sync pair remains
//     (8 barriers per 100 taps instead of ~104).
//   - LDS traffic drops to 8 B-reads/wave/tap -> per-CU floor ~32us.
//   - No inline-asm waitcnt: compiler emits counted lgkm/vmcnt.
//   Safety: sH RAW/WAR across chunks via __syncthreads pair (own
//   ds_reads drained by lgkmcnt(0) inside syncthreads; all waves
//   arrive -> safe to overwrite). Register WAR (bv reuse, av swap)
//   is compiler-enforced dataflow. Occupancy: LDS 30KB, ~220 regs
//   incl acc -> 2 blocks/CU held by __launch_bounds__(256,2).
//   Specialized: ntaps==25, five==1 (all phase-A jobs).
// ------------------------------------------------------------------
template<typename JOBS>
__global__ __launch_bounds__(256, 2) void hconvA_kernel(JOBS jobs)
{
    __shared__ unsigned short sH[15360];   // 4 planes x 480 cells x 8 shorts
    const int tid = threadIdx.x;

    // XCD-clustered job mapping (requires nb%8==0, gridDim.x==32)
    const int nb   = gridDim.x * gridDim.y;
    const int per8 = nb >> 3;
    const int bidl = blockIdx.x + gridDim.x * blockIdx.y;
    const int g    = (bidl & 7) * per8 + (bidl >> 3);
    const int jy   = g >> 5;
    const int xt   = g & 31;
    const HJob jb = jobs.j[jy];

    const int ng0 = xt << 8;
    const int bb = ng0 >> 10, p0 = ng0 & 1023;
    const int y0 = p0 >> 5;          // {0,8,16,24}

    const int lane = tid & 63, wv = tid >> 6;
    const int wm = (wv & 1) << 6;    // M base 0/64
    const int wn = (wv >> 1) << 7;   // N base 0/128
    const int col = lane & 31, ll5 = lane >> 5;

    int bofs0[4];
#pragma unroll
    for (int ni = 0; ni < 4; ++ni) {
        const int ln = wn + ni * 32 + col;
        const int cell = ((ln >> 5) + 2) * 40 + (ln & 31) + 4;
        bofs0[ni] = cell * 8 + ll5 * 3840;
    }

    f16v acc[2][4];
#pragma unroll
    for (int i = 0; i < 2; ++i)
#pragma unroll
        for (int j = 0; j < 4; ++j) acc[i][j] = (f16v)0.f;

    const HSeg sg = jb.s;
    const unsigned short* inb = sg.in + ((size_t)bb << (10 + sg.cl));
    // per-lane A-fragment base inside a tile: + s*2048 + mi*256
    const unsigned short* wbase = jb.wt + ll5 * 1024 + (wm + col) * 8;
    const int nch = sg.nch;

    bf8v avA[2][2], avB[2][2], bv[2][4];

    auto ldA = [&](bf8v (&av)[2][2], int gt) {
        const unsigned short* p = wbase + (size_t)gt * 4096;
        av[0][0] = *(const bf8v*)(p);
        av[0][1] = *(const bf8v*)(p + 256);
        av[1][0] = *(const bf8v*)(p + 2048);
        av[1][1] = *(const bf8v*)(p + 2048 + 256);
    };
    auto rdB = [&](int tc) {
        const int t5 = (tc * 52) >> 8;
        const int tO = ((t5 - 2) * 40 + (tc - t5 * 5 - 2)) * 8;
#pragma unroll
        for (int s = 0; s < 2; ++s)
#pragma unroll
            for (int ni = 0; ni < 4; ++ni)
                bv[s][ni] = *(const bf8v*)&sH[bofs0[ni] + tO + s * 7680];
    };
    auto mm = [&](bf8v (&av)[2][2]) {
        __builtin_amdgcn_s_setprio(1);
#pragma unroll
        for (int s = 0; s < 2; ++s)
#pragma unroll
            for (int mi = 0; mi < 2; ++mi)
#pragma unroll
                for (int ni = 0; ni < 4; ++ni)
                    acc[mi][ni] = __builtin_amdgcn_mfma_f32_32x32x16_bf16(
                        av[s][mi], bv[s][ni], acc[mi][ni], 0, 0, 0);
        __builtin_amdgcn_s_setprio(0);
    };

    stage_halo(sH, inb, sg.cl, sg.c0, y0, tid);
    __syncthreads();                 // sH visible to all waves

    for (int c = 0; c < nch; ++c) {
        if (c > 0) {
            __syncthreads();         // all waves done reading sH (lgkm drained)
            stage_halo(sH, inb, sg.cl, sg.c0 + c * 32, y0, tid);
            __syncthreads();         // new sH visible
        }
        const int gt0 = c * 25;
        ldA(avA, gt0);
        for (int jj = 0; jj < 12; ++jj) {
            ldA(avB, gt0 + 2 * jj + 1);
            rdB(2 * jj);     mm(avA);
            ldA(avA, gt0 + 2 * jj + 2);
            rdB(2 * jj + 1); mm(avB);
        }
        rdB(24); mm(avA);
    }

    // epilogue (32x32 C/D): col=lane&31, row=(reg&3)+8*(reg>>2)+4*ll5
    const int nfix = ng0 + wn + col;
#pragma unroll
    for (int ni = 0; ni < 4; ++ni) {
        const int n = nfix + ni * 32;
        float* ob = jb.out + (size_t)n * jb.cout_stride;
#pragma unroll
        for (int mi = 0; mi < 2; ++mi) {
            const int mb = wm + mi * 32 + 4 * ll5;
            const f16v a = acc[mi][ni];
#pragma unroll
            for (int qd = 0; qd < 4; ++qd) {
                f4v v;
                v[0] = a[qd * 4 + 0]; v[1] = a[qd * 4 + 1];
                v[2] = a[qd * 4 + 2]; v[3] = a[qd * 4 + 3];
                *(f4v*)(ob + mb + qd * 8) = v;
            }
        }
    }
}

// ------------------------------------------------------------------
// hconv: classic 2-phase stream conv (phase B: many short jobs, 576
// blocks). sH plane layout (4 planes x 320 cells x 8 shorts).
// ------------------------------------------------------------------
template<typename JOBS>
__global__ __launch_bounds__(256) void hconv_kernel(JOBS jobs)
{
    __shared__ unsigned short sA[8192];    // 2 x 8KB tile buffers
    __shared__ unsigned short sH[10240];   // 4 planes x 320 cells x 8 shorts
    const HJob jb = jobs.j[blockIdx.y];
    const int tid = threadIdx.x;

    const int ng0 = blockIdx.x * 128;
    const int bb = ng0 >> 10, p0 = ng0 & 1023;
    const int y0 = p0 >> 5;

    const int lane = tid & 63, wv = tid >> 6;
    const int wm = (wv & 1) << 6;
    const int wn = (wv >> 1) << 6;
    const int col = lane & 31, ll5 = lane >> 5;

    int bofs0[2];
#pragma unroll
    for (int ni = 0; ni < 2; ++ni) {
        const int ln = wn + ni * 32 + col;
        const int cell = ((ln >> 5) + 2) * 40 + (ln & 31) + 4;
        bofs0[ni] = cell * 8 + ll5 * 2560;
    }

    f16v acc[2][2];
#pragma unroll
    for (int i = 0; i < 2; ++i)
#pragma unroll
        for (int j = 0; j < 2; ++j) acc[i][j] = (f16v)0.f;

    const HSeg sg = jb.s;
    const unsigned short* inb = sg.in + ((size_t)bb << (10 + sg.cl));
    const unsigned short* wptr = jb.wt;
    int buf = 0;
    bool first = true;
    for (int ch = 0; ch < sg.nch; ++ch) {
        const int c0 = sg.c0 + ch * 32;
#pragma unroll
        for (int k = 0; k < 5; ++k) {
            const int s = tid + k * 256;
            const int r = s / 160;
            const int rem = s - r * 160;
            const int cc = rem >> 2, G = rem & 3;
            const int y = y0 + r - 2, x = cc - 4;
            const bool okv = ((unsigned)y < 32u) & ((unsigned)x < 32u);
            const int yc = okv ? y : 0, xc = okv ? x : 0;
            bf8v v = *(const bf8v*)(inb + ((((yc << 5) + xc)) << sg.cl) + c0 + G * 8);
            if (!okv) v = (bf8v)(short)0;
            *(bf8v*)&sH[(G * 320 + r * 40 + cc) * 8] = v;
        }
        if (first) {
            GLDS(wptr + tid * 8,         &sA[tid * 8]);
            GLDS(wptr + (tid + 256) * 8, &sA[(tid + 256) * 8]);
            wptr += 4096;
            first = false;
        }
        __syncthreads();
        for (int t = 0; t < sg.ntaps; ++t) {
            GLDS(wptr + tid * 8,         &sA[(buf ^ 1) * 4096 + tid * 8]);
            GLDS(wptr + (tid + 256) * 8, &sA[(buf ^ 1) * 4096 + (tid + 256) * 8]);
            wptr += 4096;
            int tO = 0;
            if (sg.five) {
                const int tap = sg.tap0 + t;
                const int t5 = (tap * 52) >> 8;
                tO = ((t5 - 2) * 40 + (tap - t5 * 5 - 2)) * 8;
            }
            const unsigned short* sAb = &sA[buf * 4096];
#pragma unroll
            for (int s = 0; s < 2; ++s) {
                const int o = s * 2 + ll5;
                bf8v av[2], bv[2];
#pragma unroll
                for (int mi = 0; mi < 2; ++mi)
                    av[mi] = *(const bf8v*)&sAb[(o * 128 + wm + mi * 32 + col) * 8];
#pragma unroll
                for (int ni = 0; ni < 2; ++ni)
                    bv[ni] = *(const bf8v*)&sH[bofs0[ni] + tO + s * 5120];
#pragma unroll
                for (int mi = 0; mi < 2; ++mi)
#pragma unroll
                    for (int ni = 0; ni < 2; ++ni)
                        acc[mi][ni] = __builtin_amdgcn_mfma_f32_32x32x16_bf16(
                            av[mi], bv[ni], acc[mi][ni], 0, 0, 0);
            }
            __syncthreads();
            buf ^= 1;
        }
    }

    const int nfix = ng0 + wn + col;
#pragma unroll
    for (int ni = 0; ni < 2; ++ni) {
        const int n = nfix + ni * 32;
        float* ob = jb.out + (size_t)n * jb.cout_stride;
#pragma unroll
        for (int mi = 0; mi < 2; ++mi) {
            const int mb = wm + mi * 32 + 4 * ll5;
            const f16v a = acc[mi][ni];
#pragma unroll
            for (int qd = 0; qd < 4; ++qd) {
                f4v v;
                v[0] = a[qd * 4 + 0]; v[1] = a[qd * 4 + 1];
                v[2] = a[qd * 4 + 2]; v[3] = a[qd * 4 + 3];
                *(f4v*)(ob + mb + qd * 8) = v;
            }
        }
    }
}

// ------------------------------------------------------------------
// packT: OIHW f32 -> linear tile stream [at][oct][row][8] bf16.
// ------------------------------------------------------------------
__global__ __launch_bounds__(256) void packT_kernel(
    const float* __restrict__ src, unsigned short* __restrict__ dst,
    int Cin, int srcTaps, int rowOff, int ci0, int ntaps, int tap0,
    int ciMax, int total)
{
    const int idx = blockIdx.x * 256 + threadIdx.x;
    if (idx >= total) return;
    const int j = idx & 7;
    const int row = (idx >> 3) & 127;
    const int q = (idx >> 10) & 3;
    const int at = idx >> 12;
    const int ch = at / ntaps;
    const int tap = tap0 + (at - ch * ntaps);
    const int ci = ci0 + ch * 32 + q * 8 + j;
    float v = 0.f;
    if (ci < ciMax)
        v = src[((size_t)(rowOff + row) * Cin + ci) * srcTaps + tap];
    dst[idx] = f2bf(v);
}

__global__ __launch_bounds__(256) void net_kernel(
    const float* __restrict__ frames, const float* __restrict__ mask,
    const float* __restrict__ xgen, unsigned short* __restrict__ net, int t)
{
    const int idx = blockIdx.x * 256 + threadIdx.x;  // 8192*32
    const int n = idx >> 5, ch = idx & 31;
    float v = 0.f;
    if (ch < 16) {
        const int b = n >> 10, p = n & 1023;
        const float fr = frames[((((size_t)b * 20 + t) << 10) + p) * 16 + ch];
        if (t < TPREV) v = fr;
        else {
            const float mk = mask[((((size_t)b * 9 + (t - TPREV)) << 10) + p) * 16 + ch];
            v = mk * fr + (1.f - mk) * xgen[(size_t)n * 16 + ch];
        }
    }
    net[idx] = f2bf(v);
}

__global__ __launch_bounds__(256) void gates_kernel(
    const float* __restrict__ preA, const float* __restrict__ preB,
    float* __restrict__ c, float* __restrict__ m,
    unsigned short* __restrict__ m_bf, unsigned short* __restrict__ mem)
{
    const int idx = blockIdx.x * 256 + threadIdx.x;  // 8192*128
    const int n = idx >> 7, ch = idx & 127;
    const float* pa = preA + (size_t)n * 896 + ch;
    const float* pb = preB + (size_t)n * 896 + ch;
    const float i_ = pa[0]   + pb[0];
    const float f_ = pa[128] + pb[128];
    const float g_ = pa[256] + pb[256];
    const float ip = pa[384] + pb[384];
    const float fp = pa[512] + pb[512];
    const float gp = pa[640] + pb[640];
    const float cn = sigmoidf_(f_ + 1.f) * c[idx] + sigmoidf_(i_) * tanhf(g_);
    const float mn = sigmoidf_(fp + 1.f) * m[idx] + sigmoidf_(ip) * tanhf(gp);
    c[idx] = cn;
    m[idx] = mn;
    m_bf[idx] = f2bf(mn);
    mem[(size_t)n * 256 + ch] = f2bf(cn);
    mem[(size_t)n * 256 + 128 + ch] = f2bf(mn);
}

__global__ __launch_bounds__(256) void hout_kernel(
    const float* __restrict__ preA, const float* __restrict__ preB,
    const float* __restrict__ opart, const float* __restrict__ lconv,
    unsigned short* __restrict__ h)
{
    const int idx = blockIdx.x * 256 + threadIdx.x;  // 8192*128
    const int n = idx >> 7, ch = idx & 127;
    float oc = preA[(size_t)n * 896 + 768 + ch] + preB[(size_t)n * 896 + 768 + ch];
#pragma unroll
    for (int j = 0; j < 8; ++j) oc += opart[idx + (size_t)j * 1048576];
    h[idx] = f2bf(sigmoidf_(oc) * tanhf(lconv[idx]));
}

__global__ __launch_bounds__(256) void wout_kernel(
    const unsigned short* __restrict__ h3, const float* __restrict__ wo,
    float* __restrict__ xgen, float* __restrict__ out, int t)
{
    const int idx = blockIdx.x * 256 + threadIdx.x;  // 8192*16
    const int n = idx >> 4, ch = idx & 15;
    const int b = n >> 10, p = n & 1023;
    const unsigned short* hr = h3 + (size_t)n * 128;
    const float* wr = wo + ch * 128;
    float acc = 0.f;
#pragma unroll 8
    for (int ci = 0; ci < 128; ++ci)
        acc = fmaf(bf2f(hr[ci]), wr[ci], acc);
    xgen[idx] = acc;
    out[((((size_t)b * TT + t) << 10) + p) * 16 + ch] = acc;
}

extern "C" void kernel_launch(void* const* d_in, const int* in_sizes, int n_in,
                              void* d_out, int out_size, void* d_ws, size_t ws_size,
                              hipStream_t stream)
{
    const float* frames = (const float*)d_in[0];
    const float* mask   = (const float*)d_in[1];
    const float* Wx0    = (const float*)d_in[2];
    const float* Wx     = (const float*)d_in[3];
    const float* Wh     = (const float*)d_in[4];
    const float* Wm     = (const float*)d_in[5];
    const float* Wo     = (const float*)d_in[6];
    const float* Wl     = (const float*)d_in[7];
    const float* Wout   = (const float*)d_in[8];
    float* out = (float*)d_out;

    char* base = (char*)d_ws;
    size_t off = 0;
    auto take = [&](size_t bytes) -> char* {
        char* p = base + off;
        off = (off + bytes + 255) & ~(size_t)255;
        return p;
    };
    // ---- zero-init region ----
    float* c0            = (float*)take(4ull * 1048576 * 4);
    float* m32           = (float*)take((size_t)1048576 * 4);
    unsigned short* hbf  = (unsigned short*)take(4ull * 1048576 * 2);
    unsigned short* mbf  = (unsigned short*)take((size_t)1048576 * 2);
    const size_t zbytes = off;
    // ---- working buffers ----
    float* xgen          = (float*)take((size_t)131072 * 4);
    float* preA          = (float*)take((size_t)8192 * 896 * 4);
    float* preB          = (float*)take((size_t)8192 * 896 * 4);
    float* lconv         = (float*)take((size_t)1048576 * 4);
    float* opart         = (float*)take(8ull * 1048576 * 4);
    unsigned short* net  = (unsigned short*)take((size_t)262144 * 2);   // [8192][32]
    unsigned short* mem  = (unsigned short*)take((size_t)2097152 * 2);
    // ---- packed weights (tile streams; +4096 el pad) ----
    unsigned short* pa0xT = (unsigned short*)take(((size_t)7 * 25 * 4096 + 4096) * 2);
    unsigned short* paT0 = (unsigned short*)take(((size_t)7 * 100 * 4096 + 4096) * 2);
    unsigned short* paT1 = (unsigned short*)take(((size_t)7 * 200 * 4096 + 4096) * 2);
    unsigned short* paT2 = (unsigned short*)take(((size_t)7 * 200 * 4096 + 4096) * 2);
    unsigned short* paT3 = (unsigned short*)take(((size_t)7 * 200 * 4096 + 4096) * 2);
    unsigned short* paT[4] = { paT0, paT1, paT2, paT3 };
    unsigned short* oT   = (unsigned short*)take((4ull * 200 * 4096 + 4096) * 2);
    unsigned short* lT   = (unsigned short*)take((4ull * 8 * 4096 + 4096) * 2);

    hipMemsetAsync(d_ws, 0, zbytes, stream);

    auto packT = [&](const float* s, unsigned short* d, int Cin, int srcTaps,
                     int rowOff, int ci0, int nch, int ntaps, int tap0, int ciMax) {
        const int total = nch * ntaps * 4096;
        packT_kernel<<<(total + 255) / 256, 256, 0, stream>>>(
            s, d, Cin, srcTaps, rowOff, ci0, ntaps, tap0, ciMax, total);
    };
    const int CIMAXBIG = 1 << 30;
    for (int g = 0; g < 7; ++g) {
        packT(Wx0, pa0xT + (size_t)g * 25 * 4096, 16, 25, g * 128, 0, 1, 25, 0, 16);
        const float* hm0 = (g < 3) ? (Wh + (size_t)g * 128 * 128 * 25)
                         : (g == 6) ? (Wh + (size_t)384 * 128 * 25)
                                    : (Wm + (size_t)(g - 3) * 128 * 128 * 25);
        packT(hm0, paT0 + (size_t)g * 100 * 4096, 128, 25, 0, 0, 4, 25, 0, CIMAXBIG);
        for (int l = 1; l < 4; ++l) {
            packT(Wx + (size_t)(l - 1) * 896 * 128 * 25,
                  paT[l] + (size_t)g * 200 * 4096, 128, 25, g * 128, 0, 4, 25, 0, CIMAXBIG);
            const float* hmsrc = (g < 3) ? (Wh + ((size_t)l * 512 + g * 128) * 128 * 25)
                               : (g == 6) ? (Wh + ((size_t)l * 512 + 384) * 128 * 25)
                                          : (Wm + ((size_t)l * 384 + (g - 3) * 128) * 128 * 25);
            packT(hmsrc, paT[l] + ((size_t)g * 200 + 100) * 4096, 128, 25, 0, 0, 4, 25, 0, CIMAXBIG);
        }
    }
    for (int l = 0; l < 4; ++l) {
        packT(Wo + (size_t)l * 128 * 256 * 25, oT + (size_t)l * 200 * 4096,
              256, 25, 0, 0, 8, 25, 0, CIMAXBIG);
        packT(Wl + (size_t)l * 128 * 256, lT + (size_t)l * 8 * 4096,
              256, 1, 0, 0, 8, 1, 0, CIMAXBIG);
    }

    for (int t = 0; t < TT; ++t) {
        net_kernel<<<1024, 256, 0, stream>>>(frames, mask, xgen, net, t);
        for (int l = 0; l < 4; ++l) {
            unsigned short* hl = hbf + (size_t)l * 1048576;
            // ---- phase A: one hconvA dispatch of 14 jobs ----
            HJobs14 JA{};
            if (l == 0) {
                for (int g = 0; g < 7; ++g) {
                    const unsigned short* hmsrc = (g < 3 || g == 6) ? hl : mbf;
                    JA.j[2 * g] = HJob{ pa0xT + (size_t)g * 25 * 4096, preA + g * 128,
                                        896, 0, HSeg{ net, 5, 0, 1, 0, 25, 1 } };
                    JA.j[2 * g + 1] = HJob{ paT0 + (size_t)g * 100 * 4096, preB + g * 128,
                                            896, 0, HSeg{ hmsrc, 7, 0, 4, 0, 25, 1 } };
                }
            } else {
                for (int g = 0; g < 7; ++g) {
                    const unsigned short* hmsrc = (g < 3 || g == 6) ? hl : mbf;
                    JA.j[g] = HJob{ paT[l] + (size_t)g * 200 * 4096, preA + g * 128,
                                    896, 0, HSeg{ hbf + (size_t)(l - 1) * 1048576, 7, 0, 4, 0, 25, 1 } };
                    JA.j[7 + g] = HJob{ paT[l] + ((size_t)g * 200 + 100) * 4096, preB + g * 128,
                                        896, 0, HSeg{ hmsrc, 7, 0, 4, 0, 25, 1 } };
                }
            }
            hconvA_kernel<HJobs14><<<dim3(32, 14), 256, 0, stream>>>(JA);

            gates_kernel<<<4096, 256, 0, stream>>>(preA, preB,
                c0 + (size_t)l * 1048576, m32, mbf, mem);

            // ---- phase B: o-conv split by ci-chunk x8 + lconv (classic kernel)
            HJobs9 JB{};
            for (int jj = 0; jj < 8; ++jj)
                JB.j[jj] = HJob{ oT + ((size_t)l * 200 + jj * 25) * 4096,
                                 opart + (size_t)jj * 1048576, 128, 0,
                                 HSeg{ mem, 8, jj * 32, 1, 0, 25, 1 } };
            JB.j[8] = HJob{ lT + (size_t)l * 8 * 4096, lconv, 128, 0,
                            HSeg{ mem, 8, 0, 8, 0, 1, 0 } };
            hconv_kernel<HJobs9><<<dim3(64, 9), 256, 0, stream>>>(JB);

            hout_kernel<<<4096, 256, 0, stream>>>(preA, preB, opart, lconv, hl);
        }
        wout_kernel<<<512, 256, 0, stream>>>(hbf + (size_t)3 * 1048576, Wout, xgen, out, t);
    }
}